// Round 5
// baseline (1643.156 us; speedup 1.0000x reference)
//
#include <hip/hip_runtime.h>

typedef unsigned short u16;
typedef __bf16 bf16x8 __attribute__((ext_vector_type(8)));
typedef float f32x4 __attribute__((ext_vector_type(4)));

#define B_SZ   4096
#define H_NUM  32
#define F_DIM  1024
#define NTOT   (H_NUM * F_DIM)   // 32768
#define N_CAT  8
#define CAT_D  16
#define N_CONT 24
#define LN_EPS 1e-5f
#define NSTRIP (NTOT / 128)      // 256 n-strips in the GEMM

__device__ __forceinline__ u16 f2bf(float f) {
    unsigned int u = __builtin_bit_cast(unsigned int, f);
    unsigned int r = (u + 0x7FFFu + ((u >> 16) & 1u)) >> 16;
    return (u16)r;
}

__device__ __forceinline__ void gl2lds16(const void* g, void* l) {
    __builtin_amdgcn_global_load_lds(
        (const __attribute__((address_space(1))) void*)g,
        (__attribute__((address_space(3))) void*)l,
        16, 0, 0);
}

__device__ __forceinline__ float wave_sum(float v) {
#pragma unroll
    for (int o = 32; o; o >>= 1) v += __shfl_xor(v, o);
    return v;
}

// ---------------- z f32 -> bf16 ----------------
__global__ __launch_bounds__(256) void zconv(const float* __restrict__ z,
                                             u16* __restrict__ zb) {
    int i = blockIdx.x * 256 + threadIdx.x;      // one float4 per thread
    float4 v = ((const float4*)z)[i];
    ushort4 o;
    o.x = f2bf(v.x); o.y = f2bf(v.y); o.z = f2bf(v.z); o.w = f2bf(v.w);
    ((ushort4*)zb)[i] = o;
}

// ---------------- W_proj [h][f][d] f32 -> Wt [h][d][f] bf16 ----------------
__global__ __launch_bounds__(256) void transpose_w(const float* __restrict__ W,
                                                   u16* __restrict__ Wt) {
    __shared__ u16 tile[64][72];
    const int h = blockIdx.z;
    const int f0 = blockIdx.x * 64;
    const int d0 = blockIdx.y * 64;
    const float* Wh = W + (size_t)h * F_DIM * F_DIM;
    u16* Wth = Wt + (size_t)h * F_DIM * F_DIM;
    const int t = threadIdx.x;

#pragma unroll
    for (int i = 0; i < 4; ++i) {
        int idx = i * 256 + t;        // 0..1023
        int fr = idx >> 4;            // 0..63
        int c4 = idx & 15;            // 0..15
        float4 v = *(const float4*)(Wh + (size_t)(f0 + fr) * F_DIM + d0 + c4 * 4);
        tile[fr][c4 * 4 + 0] = f2bf(v.x);
        tile[fr][c4 * 4 + 1] = f2bf(v.y);
        tile[fr][c4 * 4 + 2] = f2bf(v.z);
        tile[fr][c4 * 4 + 3] = f2bf(v.w);
    }
    __syncthreads();
#pragma unroll
    for (int i = 0; i < 2; ++i) {
        int idx = i * 256 + t;        // 0..511
        int dr = idx >> 3;            // 0..63
        int c8 = idx & 7;             // 0..7
        __attribute__((aligned(16))) u16 tmp[8];
#pragma unroll
        for (int j = 0; j < 8; ++j) tmp[j] = tile[c8 * 8 + j][dr];
        *(uint4*)(Wth + (size_t)(d0 + dr) * F_DIM + f0 + c8 * 8) = *(const uint4*)tmp;
    }
}

// ---------------- GEMM + per-block LN partial sums ----------------
// Block order: xcd = wg&7 owns n-strips [xcd*32, xcd*32+32); within the XCD,
// m iterates fastest so the 256KB B-strip stays hot in that XCD's L2 and the
// 8MB A panel lives in L3.
__global__ __launch_bounds__(256) void gemm_bt(const u16* __restrict__ A,
                                               const u16* __restrict__ Bt,
                                               const float* __restrict__ bproj,
                                               float* __restrict__ C,
                                               float* __restrict__ psum,
                                               float* __restrict__ psumsq) {
    __shared__ u16 sA[128 * 64];
    __shared__ u16 sB[128 * 64];
    const int t = threadIdx.x;
    const int wid = t >> 6;
    const int lane = t & 63;
    const int l16 = lane & 15;
    const int lk = lane >> 4;
    const int wr = wid >> 1;
    const int wc = wid & 1;

    const int wg = blockIdx.x;
    const int xcd = wg & 7;
    const int local = wg >> 3;              // 0..1023
    const int n0 = (xcd * 32 + (local >> 5)) * 128;   // n-strip: slow within XCD
    const int m0 = (local & 31) * 128;                // m-strip: fast within XCD

    f32x4 acc[4][4];
    const f32x4 zero = {0.f, 0.f, 0.f, 0.f};
#pragma unroll
    for (int m = 0; m < 4; ++m)
#pragma unroll
        for (int n = 0; n < 4; ++n) acc[m][n] = zero;

    for (int k0 = 0; k0 < 1024; k0 += 64) {
#pragma unroll
        for (int q2 = 0; q2 < 4; ++q2) {
            int ci = q2 * 256 + t;
            int r = ci >> 3, c8 = ci & 7;
            gl2lds16(A + ((size_t)(m0 + r) << 10) + k0 + c8 * 8,
                     sA + (size_t)(q2 * 256 + (wid << 6)) * 8);
        }
#pragma unroll
        for (int q2 = 0; q2 < 4; ++q2) {
            int ci = q2 * 256 + t;
            int r = ci >> 3, c8 = ci & 7;
            gl2lds16(Bt + ((size_t)(n0 + r) << 10) + k0 + c8 * 8,
                     sB + (size_t)(q2 * 256 + (wid << 6)) * 8);
        }
        __syncthreads();
#pragma unroll
        for (int kk = 0; kk < 64; kk += 32) {
            bf16x8 a[4], bf[4];
#pragma unroll
            for (int m = 0; m < 4; ++m)
                a[m] = *(const bf16x8*)(sA + (wr * 64 + m * 16 + l16) * 64 + kk + lk * 8);
#pragma unroll
            for (int n = 0; n < 4; ++n)
                bf[n] = *(const bf16x8*)(sB + (wc * 64 + n * 16 + l16) * 64 + kk + lk * 8);
#pragma unroll
            for (int m = 0; m < 4; ++m)
#pragma unroll
                for (int n = 0; n < 4; ++n)
                    acc[m][n] = __builtin_amdgcn_mfma_f32_16x16x32_bf16(a[m], bf[n], acc[m][n], 0, 0, 0);
        }
        __syncthreads();
    }

    // epilogue: C-write + per-row (sum, sumsq) over this block's 128 cols.
    // Reduction scratch aliases dead sA (keeps LDS at 32KB -> 5 blocks/CU).
    float* rbuf = (float*)sA;   // [0..255]: sum[wc][r], [256..511]: sumsq[wc][r]

    float sm[4][4], s2m[4][4];
#pragma unroll
    for (int m = 0; m < 4; ++m)
#pragma unroll
        for (int j = 0; j < 4; ++j) { sm[m][j] = 0.f; s2m[m][j] = 0.f; }

#pragma unroll
    for (int n = 0; n < 4; ++n) {
        int col = n0 + wc * 64 + n * 16 + l16;
        float bias = bproj[col];
#pragma unroll
        for (int m = 0; m < 4; ++m) {
            int rbase = m0 + wr * 64 + m * 16 + lk * 4;
#pragma unroll
            for (int j = 0; j < 4; ++j) {
                float v = acc[m][n][j] + bias;
                C[(size_t)(rbase + j) * NTOT + col] = v;
                sm[m][j] += v;
                s2m[m][j] += v * v;
            }
        }
    }
    // reduce over the 16 l16 lanes (same rows, different cols)
#pragma unroll
    for (int o = 1; o < 16; o <<= 1) {
#pragma unroll
        for (int m = 0; m < 4; ++m)
#pragma unroll
            for (int j = 0; j < 4; ++j) {
                sm[m][j] += __shfl_xor(sm[m][j], o);
                s2m[m][j] += __shfl_xor(s2m[m][j], o);
            }
    }
    if (l16 == 0) {
#pragma unroll
        for (int m = 0; m < 4; ++m)
#pragma unroll
            for (int j = 0; j < 4; ++j) {
                int r = wr * 64 + m * 16 + lk * 4 + j;
                rbuf[wc * 128 + r] = sm[m][j];
                rbuf[256 + wc * 128 + r] = s2m[m][j];
            }
    }
    __syncthreads();
    if (t < 128) {
        int strip = n0 >> 7;
        psum[(size_t)(m0 + t) * NSTRIP + strip] = rbuf[t] + rbuf[128 + t];
        psumsq[(size_t)(m0 + t) * NSTRIP + strip] = rbuf[256 + t] + rbuf[384 + t];
    }
}

// ---------------- finalize LN stats from partials ----------------
__global__ __launch_bounds__(256) void ln_finalize(const float* __restrict__ psum,
                                                   const float* __restrict__ psumsq,
                                                   float* __restrict__ murs) {
    const int b = blockIdx.x;
    const int t = threadIdx.x;
    float s = psum[(size_t)b * NSTRIP + t];
    float s2 = psumsq[(size_t)b * NSTRIP + t];
    s = wave_sum(s);
    s2 = wave_sum(s2);
    __shared__ float red[8];
    int wid = t >> 6, lane = t & 63;
    if (lane == 0) { red[wid] = s; red[4 + wid] = s2; }
    __syncthreads();
    if (t == 0) {
        float S = red[0] + red[1] + red[2] + red[3];
        float S2 = red[4] + red[5] + red[6] + red[7];
        float m = S / (float)NTOT;
        float var = S2 / (float)NTOT - m * m;
        murs[b] = m;
        murs[B_SZ + b] = rsqrtf(var + LN_EPS);
    }
}

// ---------------- normalize + relu + heads: one 256-thread block per b ----------------
// Iteration k covers head k exactly: i = 256k + t (coalesced float4s).
__global__ __launch_bounds__(256, 8) void headsG(float* __restrict__ lat_base,
                                                 const float* __restrict__ murs,
                                                 const float* __restrict__ lnw,
                                                 const float* __restrict__ lnb,
                                                 const float* __restrict__ Wcat,
                                                 const float* __restrict__ bcat,
                                                 const float* __restrict__ Wcont,
                                                 const float* __restrict__ bcont,
                                                 float* __restrict__ pcat,
                                                 float* __restrict__ pcont) {
    const int b = blockIdx.x;
    const int t = threadIdx.x;
    const int lane = t & 63;
    const int w4 = t >> 6;                    // wave 0..3
    const float mu = murs[b];
    const float rs = murs[B_SZ + b];
    float4* lat4 = (float4*)(lat_base + (size_t)b * NTOT);
    const float4* lnw4 = (const float4*)lnw;
    const float4* lnb4 = (const float4*)lnb;
    const float4* wcont4 = (const float4*)Wcont;

    __shared__ float4 sy4[256];               // one head row of y
    __shared__ float cred[4][N_CAT][CAT_D];   // per-wave cat partials
    __shared__ float nred[N_CONT][4];         // per-wave cont partials

    // ---- categorical heads (k = h = 0..7): stage y in LDS, short-reduce GEMV ----
    for (int k = 0; k < N_CAT; ++k) {
        const int i = (k << 8) + t;
        float4 x = lat4[i];
        float4 w = lnw4[i];
        float4 bv = lnb4[i];
        float4 yo;
        yo.x = fmaxf(0.f, (x.x - mu) * rs * w.x + bv.x);
        yo.y = fmaxf(0.f, (x.y - mu) * rs * w.y + bv.y);
        yo.z = fmaxf(0.f, (x.z - mu) * rs * w.z + bv.z);
        yo.w = fmaxf(0.f, (x.w - mu) * rs * w.w + bv.w);
        lat4[i] = yo;
        sy4[t] = yo;
        __syncthreads();

        const int c = t & 15;                 // category column
        const int g = t >> 4;                 // f-group: f = g*64 .. g*64+63
        const float* Wc = Wcat + (size_t)k * F_DIM * CAT_D + c;
        float acc = 0.f;
#pragma unroll
        for (int j = 0; j < 16; ++j) {
            float4 yv = sy4[g * 16 + j];
            int fb = (g * 64 + j * 4) * CAT_D;
            acc += yv.x * Wc[fb] + yv.y * Wc[fb + CAT_D] +
                   yv.z * Wc[fb + 2 * CAT_D] + yv.w * Wc[fb + 3 * CAT_D];
        }
        acc += __shfl_xor(acc, 16);
        acc += __shfl_xor(acc, 32);
        if (lane < 16) cred[w4][k][lane] = acc;
        __syncthreads();
    }

    // ---- continuous heads (k = 8..31): barrier-free streaming ----
#pragma unroll 2
    for (int k = N_CAT; k < H_NUM; ++k) {
        const int i = (k << 8) + t;
        float4 x = lat4[i];
        float4 w = lnw4[i];
        float4 bv = lnb4[i];
        float4 yo;
        yo.x = fmaxf(0.f, (x.x - mu) * rs * w.x + bv.x);
        yo.y = fmaxf(0.f, (x.y - mu) * rs * w.y + bv.y);
        yo.z = fmaxf(0.f, (x.z - mu) * rs * w.z + bv.z);
        yo.w = fmaxf(0.f, (x.w - mu) * rs * w.w + bv.w);
        lat4[i] = yo;
        float4 wv = wcont4[((k - N_CAT) << 8) + t];
        float part = yo.x * wv.x + yo.y * wv.y + yo.z * wv.z + yo.w * wv.w;
        part = wave_sum(part);
        if (lane == 0) nred[k - N_CAT][w4] = part;
    }
    __syncthreads();

    // ---- finalize ----
    if (t < 128) {                            // cat softmax: h = t>>4, c = t&15
        const int h = t >> 4, c = t & 15;
        float lg = cred[0][h][c] + cred[1][h][c] + cred[2][h][c] + cred[3][h][c] +
                   bcat[h * CAT_D + c];
        float mx = lg;
#pragma unroll
        for (int o = 8; o; o >>= 1) mx = fmaxf(mx, __shfl_xor(mx, o, 16));
        float e = __expf(lg - mx);
        float sm2 = e;
#pragma unroll
        for (int o = 8; o; o >>= 1) sm2 += __shfl_xor(sm2, o, 16);
        pcat[(size_t)b * (N_CAT * CAT_D) + t] = e / sm2;
    } else if (t >= 128 && t < 128 + N_CONT) {
        const int ci = t - 128;
        pcont[(size_t)b * N_CONT + ci] =
            nred[ci][0] + nred[ci][1] + nred[ci][2] + nred[ci][3] + bcont[ci];
    }
}

extern "C" void kernel_launch(void* const* d_in, const int* in_sizes, int n_in,
                              void* d_out, int out_size, void* d_ws, size_t ws_size,
                              hipStream_t stream) {
    const float* z     = (const float*)d_in[0];
    // d_in[1] = edge (unused by reference computation)
    const float* Wp    = (const float*)d_in[2];
    const float* bp    = (const float*)d_in[3];
    const float* lnw   = (const float*)d_in[4];
    const float* lnb   = (const float*)d_in[5];
    const float* Wcat  = (const float*)d_in[6];
    const float* bcat  = (const float*)d_in[7];
    const float* Wcont = (const float*)d_in[8];
    const float* bcont = (const float*)d_in[9];

    float* out    = (float*)d_out;
    float* pcat   = out;                                   // [4096, 8, 16]
    float* pcont  = out + (size_t)B_SZ * N_CAT * CAT_D;    // [4096, 24, 1]
    float* latent = pcont + (size_t)B_SZ * N_CONT;         // [4096, 32, 1024]

    u16* zb     = (u16*)d_ws;                              // 4096*1024 bf16 (8 MB)
    u16* Wt     = zb + (size_t)B_SZ * F_DIM;               // 32768*1024 bf16 (64 MB)
    float* murs = (float*)(Wt + (size_t)NTOT * F_DIM);     // 2*4096 f32
    float* psum   = murs + 2 * B_SZ;                       // [4096][256] f32 (4 MB)
    float* psumsq = psum + (size_t)B_SZ * NSTRIP;          // [4096][256] f32 (4 MB)

    zconv<<<dim3(B_SZ * F_DIM / 1024), 256, 0, stream>>>(z, zb);
    transpose_w<<<dim3(16, 16, 32), 256, 0, stream>>>(Wp, Wt);
    gemm_bt<<<dim3(NSTRIP * (B_SZ / 128)), 256, 0, stream>>>(zb, Wt, bp, latent, psum, psumsq);
    ln_finalize<<<dim3(B_SZ), 256, 0, stream>>>(psum, psumsq, murs);
    headsG<<<dim3(B_SZ), 256, 0, stream>>>(latent, murs, lnw, lnb, Wcat, bcat,
                                           Wcont, bcont, pcat, pcont);
}

// Round 6
// 962.874 us; speedup vs baseline: 1.7065x; 1.7065x over previous
//
#include <hip/hip_runtime.h>

typedef unsigned short u16;
typedef __bf16 bf16x8 __attribute__((ext_vector_type(8)));
typedef float f32x4 __attribute__((ext_vector_type(4)));

#define B_SZ   4096
#define H_NUM  32
#define F_DIM  1024
#define NTOT   (H_NUM * F_DIM)   // 32768
#define N_CAT  8
#define CAT_D  16
#define N_CONT 24
#define LN_EPS 1e-5f
#define NSTRIP (NTOT / 128)      // 256 n-strips in the GEMM

__device__ __forceinline__ u16 f2bf(float f) {
    unsigned int u = __builtin_bit_cast(unsigned int, f);
    unsigned int r = (u + 0x7FFFu + ((u >> 16) & 1u)) >> 16;
    return (u16)r;
}

__device__ __forceinline__ void gl2lds16(const void* g, void* l) {
    __builtin_amdgcn_global_load_lds(
        (const __attribute__((address_space(1))) void*)g,
        (__attribute__((address_space(3))) void*)l,
        16, 0, 0);
}

__device__ __forceinline__ float wave_sum(float v) {
#pragma unroll
    for (int o = 32; o; o >>= 1) v += __shfl_xor(v, o);
    return v;
}

// ---------------- z f32 -> bf16 ----------------
__global__ __launch_bounds__(256) void zconv(const float* __restrict__ z,
                                             u16* __restrict__ zb) {
    int i = blockIdx.x * 256 + threadIdx.x;      // one float4 per thread
    float4 v = ((const float4*)z)[i];
    ushort4 o;
    o.x = f2bf(v.x); o.y = f2bf(v.y); o.z = f2bf(v.z); o.w = f2bf(v.w);
    ((ushort4*)zb)[i] = o;
}

// ---------------- W_proj [h][f][d] f32 -> Wt [h][d][f] bf16 ----------------
__global__ __launch_bounds__(256) void transpose_w(const float* __restrict__ W,
                                                   u16* __restrict__ Wt) {
    __shared__ u16 tile[64][72];
    const int h = blockIdx.z;
    const int f0 = blockIdx.x * 64;
    const int d0 = blockIdx.y * 64;
    const float* Wh = W + (size_t)h * F_DIM * F_DIM;
    u16* Wth = Wt + (size_t)h * F_DIM * F_DIM;
    const int t = threadIdx.x;

#pragma unroll
    for (int i = 0; i < 4; ++i) {
        int idx = i * 256 + t;        // 0..1023
        int fr = idx >> 4;            // 0..63
        int c4 = idx & 15;            // 0..15
        float4 v = *(const float4*)(Wh + (size_t)(f0 + fr) * F_DIM + d0 + c4 * 4);
        tile[fr][c4 * 4 + 0] = f2bf(v.x);
        tile[fr][c4 * 4 + 1] = f2bf(v.y);
        tile[fr][c4 * 4 + 2] = f2bf(v.z);
        tile[fr][c4 * 4 + 3] = f2bf(v.w);
    }
    __syncthreads();
#pragma unroll
    for (int i = 0; i < 2; ++i) {
        int idx = i * 256 + t;        // 0..511
        int dr = idx >> 3;            // 0..63
        int c8 = idx & 7;             // 0..7
        __attribute__((aligned(16))) u16 tmp[8];
#pragma unroll
        for (int j = 0; j < 8; ++j) tmp[j] = tile[c8 * 8 + j][dr];
        *(uint4*)(Wth + (size_t)(d0 + dr) * F_DIM + f0 + c8 * 8) = *(const uint4*)tmp;
    }
}

// ---------------- GEMM + per-block LN partial sums ----------------
// Ordering: xcd = wg&7 owns n-strips [xcd*32, xcd*32+32). Within an XCD,
// blocks advance through 8x8 super-squares (m-square fastest) so the
// in-flight set is ~16 m-strips x 8 n-strips: A slice (4MB) is L3-shared
// across all XCDs, B slice (2MB) stays hot in the local L2.
__global__ __launch_bounds__(256) void gemm_bt(const u16* __restrict__ A,
                                               const u16* __restrict__ Bt,
                                               const float* __restrict__ bproj,
                                               float* __restrict__ C,
                                               float* __restrict__ psum,
                                               float* __restrict__ psumsq) {
    __shared__ u16 sA[128 * 64];
    __shared__ u16 sB[128 * 64];
    __shared__ float sred[2][128];
    __shared__ float s2red[2][128];
    const int t = threadIdx.x;
    const int wid = t >> 6;
    const int lane = t & 63;
    const int l16 = lane & 15;
    const int lk = lane >> 4;
    const int wr = wid >> 1;
    const int wc = wid & 1;

    const int wg = blockIdx.x;
    const int xcd = wg & 7;
    const int local = wg >> 3;                 // 0..1023 within XCD
    const int sq = local >> 6;                 // 16 super-squares (4 msq x 4 nsq)
    const int within = local & 63;             // 8m x 8n inside a square
    const int m0 = (((sq & 3) << 3) + (within & 7)) * 128;
    const int n0 = ((xcd << 5) + ((sq >> 2) << 3) + (within >> 3)) * 128;

    f32x4 acc[4][4];
    const f32x4 zero = {0.f, 0.f, 0.f, 0.f};
#pragma unroll
    for (int m = 0; m < 4; ++m)
#pragma unroll
        for (int n = 0; n < 4; ++n) acc[m][n] = zero;

    for (int k0 = 0; k0 < 1024; k0 += 64) {
#pragma unroll
        for (int q2 = 0; q2 < 4; ++q2) {
            int ci = q2 * 256 + t;
            int r = ci >> 3, c8 = ci & 7;
            gl2lds16(A + ((size_t)(m0 + r) << 10) + k0 + c8 * 8,
                     sA + (size_t)(q2 * 256 + (wid << 6)) * 8);
        }
#pragma unroll
        for (int q2 = 0; q2 < 4; ++q2) {
            int ci = q2 * 256 + t;
            int r = ci >> 3, c8 = ci & 7;
            gl2lds16(Bt + ((size_t)(n0 + r) << 10) + k0 + c8 * 8,
                     sB + (size_t)(q2 * 256 + (wid << 6)) * 8);
        }
        __syncthreads();
#pragma unroll
        for (int kk = 0; kk < 64; kk += 32) {
            bf16x8 a[4], bf[4];
#pragma unroll
            for (int m = 0; m < 4; ++m)
                a[m] = *(const bf16x8*)(sA + (wr * 64 + m * 16 + l16) * 64 + kk + lk * 8);
#pragma unroll
            for (int n = 0; n < 4; ++n)
                bf[n] = *(const bf16x8*)(sB + (wc * 64 + n * 16 + l16) * 64 + kk + lk * 8);
#pragma unroll
            for (int m = 0; m < 4; ++m)
#pragma unroll
                for (int n = 0; n < 4; ++n)
                    acc[m][n] = __builtin_amdgcn_mfma_f32_16x16x32_bf16(a[m], bf[n], acc[m][n], 0, 0, 0);
        }
        __syncthreads();
    }

    // epilogue: C-write (m-outer so each wave's 4 n-stores form 256B contiguous
    // runs -> full-line write combining) + per-row (sum, sumsq) partials
    float bias[4];
#pragma unroll
    for (int n = 0; n < 4; ++n) bias[n] = bproj[n0 + wc * 64 + n * 16 + l16];

    float sm[4][4], s2m[4][4];
#pragma unroll
    for (int m = 0; m < 4; ++m)
#pragma unroll
        for (int j = 0; j < 4; ++j) { sm[m][j] = 0.f; s2m[m][j] = 0.f; }

#pragma unroll
    for (int m = 0; m < 4; ++m) {
        int rbase = m0 + wr * 64 + m * 16 + lk * 4;
#pragma unroll
        for (int j = 0; j < 4; ++j) {
            float* crow = C + (size_t)(rbase + j) * NTOT + n0 + wc * 64 + l16;
#pragma unroll
            for (int n = 0; n < 4; ++n) {
                float v = acc[m][n][j] + bias[n];
                crow[n * 16] = v;
                sm[m][j] += v;
                s2m[m][j] += v * v;
            }
        }
    }
    // reduce over the 16 l16 lanes (same rows, different cols)
#pragma unroll
    for (int o = 1; o < 16; o <<= 1) {
#pragma unroll
        for (int m = 0; m < 4; ++m)
#pragma unroll
            for (int j = 0; j < 4; ++j) {
                sm[m][j] += __shfl_xor(sm[m][j], o);
                s2m[m][j] += __shfl_xor(s2m[m][j], o);
            }
    }
    if (l16 == 0) {
#pragma unroll
        for (int m = 0; m < 4; ++m)
#pragma unroll
            for (int j = 0; j < 4; ++j) {
                int r = wr * 64 + m * 16 + lk * 4 + j;
                sred[wc][r] = sm[m][j];
                s2red[wc][r] = s2m[m][j];
            }
    }
    __syncthreads();
    if (t < 128) {
        int strip = n0 >> 7;
        psum[(size_t)(m0 + t) * NSTRIP + strip] = sred[0][t] + sred[1][t];
        psumsq[(size_t)(m0 + t) * NSTRIP + strip] = s2red[0][t] + s2red[1][t];
    }
}

// ---------------- finalize LN stats from partials ----------------
__global__ __launch_bounds__(256) void ln_finalize(const float* __restrict__ psum,
                                                   const float* __restrict__ psumsq,
                                                   float* __restrict__ murs) {
    const int b = blockIdx.x;
    const int t = threadIdx.x;
    float s = psum[(size_t)b * NSTRIP + t];
    float s2 = psumsq[(size_t)b * NSTRIP + t];
    s = wave_sum(s);
    s2 = wave_sum(s2);
    __shared__ float red[8];
    int wid = t >> 6, lane = t & 63;
    if (lane == 0) { red[wid] = s; red[4 + wid] = s2; }
    __syncthreads();
    if (t == 0) {
        float S = red[0] + red[1] + red[2] + red[3];
        float S2 = red[4] + red[5] + red[6] + red[7];
        float m = S / (float)NTOT;
        float var = S2 / (float)NTOT - m * m;
        murs[b] = m;
        murs[B_SZ + b] = rsqrtf(var + LN_EPS);
    }
}

// ---------------- normalize + relu + heads: one 256-thread block per b ----------------
// Iteration k covers head k exactly: i = 256k + t (coalesced float4s).
__global__ __launch_bounds__(256) void headsG(float* __restrict__ lat_base,
                                              const float* __restrict__ murs,
                                              const float* __restrict__ lnw,
                                              const float* __restrict__ lnb,
                                              const float* __restrict__ Wcat,
                                              const float* __restrict__ bcat,
                                              const float* __restrict__ Wcont,
                                              const float* __restrict__ bcont,
                                              float* __restrict__ pcat,
                                              float* __restrict__ pcont) {
    const int b = blockIdx.x;
    const int t = threadIdx.x;
    const int lane = t & 63;
    const int w4 = t >> 6;                    // wave 0..3
    const float mu = murs[b];
    const float rs = murs[B_SZ + b];
    float4* lat4 = (float4*)(lat_base + (size_t)b * NTOT);
    const float4* lnw4 = (const float4*)lnw;
    const float4* lnb4 = (const float4*)lnb;
    const float4* wcont4 = (const float4*)Wcont;

    __shared__ float4 sy4[2][256];            // double-buffered head row of y
    __shared__ float cred[4][N_CAT][CAT_D];   // per-wave cat partials
    __shared__ float nred[N_CONT][4];         // per-wave cont partials

    // ---- categorical heads (k = h = 0..7): stage y in LDS, short-reduce GEMV ----
    for (int k = 0; k < N_CAT; ++k) {
        const int i = (k << 8) + t;
        float4 x = lat4[i];
        float4 w = lnw4[i];
        float4 bv = lnb4[i];
        float4 yo;
        yo.x = fmaxf(0.f, (x.x - mu) * rs * w.x + bv.x);
        yo.y = fmaxf(0.f, (x.y - mu) * rs * w.y + bv.y);
        yo.z = fmaxf(0.f, (x.z - mu) * rs * w.z + bv.z);
        yo.w = fmaxf(0.f, (x.w - mu) * rs * w.w + bv.w);
        lat4[i] = yo;
        sy4[k & 1][t] = yo;
        __syncthreads();

        const int c = t & 15;                 // category column
        const int g = t >> 4;                 // f-group: f = g*64 .. g*64+63
        const float* Wc = Wcat + (size_t)k * F_DIM * CAT_D + c;
        float acc = 0.f;
#pragma unroll
        for (int j = 0; j < 16; ++j) {
            float4 yv = sy4[k & 1][g * 16 + j];
            int fb = (g * 64 + j * 4) * CAT_D;
            acc += yv.x * Wc[fb] + yv.y * Wc[fb + CAT_D] +
                   yv.z * Wc[fb + 2 * CAT_D] + yv.w * Wc[fb + 3 * CAT_D];
        }
        acc += __shfl_xor(acc, 16);
        acc += __shfl_xor(acc, 32);
        if (lane < 16) cred[w4][k][lane] = acc;
        // no second barrier: next iteration writes the other sy4 buffer,
        // and the k+2 overwrite is fenced by the k+1 barrier.
    }

    // ---- continuous heads (k = 8..31): barrier-free streaming ----
#pragma unroll 2
    for (int k = N_CAT; k < H_NUM; ++k) {
        const int i = (k << 8) + t;
        float4 x = lat4[i];
        float4 w = lnw4[i];
        float4 bv = lnb4[i];
        float4 wv = wcont4[((k - N_CAT) << 8) + t];
        float4 yo;
        yo.x = fmaxf(0.f, (x.x - mu) * rs * w.x + bv.x);
        yo.y = fmaxf(0.f, (x.y - mu) * rs * w.y + bv.y);
        yo.z = fmaxf(0.f, (x.z - mu) * rs * w.z + bv.z);
        yo.w = fmaxf(0.f, (x.w - mu) * rs * w.w + bv.w);
        lat4[i] = yo;
        float part = yo.x * wv.x + yo.y * wv.y + yo.z * wv.z + yo.w * wv.w;
        part = wave_sum(part);
        if (lane == 0) nred[k - N_CAT][w4] = part;
    }
    __syncthreads();

    // ---- finalize ----
    if (t < 128) {                            // cat softmax: h = t>>4, c = t&15
        const int h = t >> 4, c = t & 15;
        float lg = cred[0][h][c] + cred[1][h][c] + cred[2][h][c] + cred[3][h][c] +
                   bcat[h * CAT_D + c];
        float mx = lg;
#pragma unroll
        for (int o = 8; o; o >>= 1) mx = fmaxf(mx, __shfl_xor(mx, o, 16));
        float e = __expf(lg - mx);
        float sm2 = e;
#pragma unroll
        for (int o = 8; o; o >>= 1) sm2 += __shfl_xor(sm2, o, 16);
        pcat[(size_t)b * (N_CAT * CAT_D) + t] = e / sm2;
    } else if (t >= 128 && t < 128 + N_CONT) {
        const int ci = t - 128;
        pcont[(size_t)b * N_CONT + ci] =
            nred[ci][0] + nred[ci][1] + nred[ci][2] + nred[ci][3] + bcont[ci];
    }
}

extern "C" void kernel_launch(void* const* d_in, const int* in_sizes, int n_in,
                              void* d_out, int out_size, void* d_ws, size_t ws_size,
                              hipStream_t stream) {
    const float* z     = (const float*)d_in[0];
    // d_in[1] = edge (unused by reference computation)
    const float* Wp    = (const float*)d_in[2];
    const float* bp    = (const float*)d_in[3];
    const float* lnw   = (const float*)d_in[4];
    const float* lnb   = (const float*)d_in[5];
    const float* Wcat  = (const float*)d_in[6];
    const float* bcat  = (const float*)d_in[7];
    const float* Wcont = (const float*)d_in[8];
    const float* bcont = (const float*)d_in[9];

    float* out    = (float*)d_out;
    float* pcat   = out;                                   // [4096, 8, 16]
    float* pcont  = out + (size_t)B_SZ * N_CAT * CAT_D;    // [4096, 24, 1]
    float* latent = pcont + (size_t)B_SZ * N_CONT;         // [4096, 32, 1024]

    u16* zb     = (u16*)d_ws;                              // 4096*1024 bf16 (8 MB)
    u16* Wt     = zb + (size_t)B_SZ * F_DIM;               // 32768*1024 bf16 (64 MB)
    float* murs = (float*)(Wt + (size_t)NTOT * F_DIM);     // 2*4096 f32
    float* psum   = murs + 2 * B_SZ;                       // [4096][256] f32 (4 MB)
    float* psumsq = psum + (size_t)B_SZ * NSTRIP;          // [4096][256] f32 (4 MB)

    zconv<<<dim3(B_SZ * F_DIM / 1024), 256, 0, stream>>>(z, zb);
    transpose_w<<<dim3(16, 16, 32), 256, 0, stream>>>(Wp, Wt);
    gemm_bt<<<dim3(NSTRIP * (B_SZ / 128)), 256, 0, stream>>>(zb, Wt, bp, latent, psum, psumsq);
    ln_finalize<<<dim3(B_SZ), 256, 0, stream>>>(psum, psumsq, murs);
    headsG<<<dim3(B_SZ), 256, 0, stream>>>(latent, murs, lnw, lnb, Wcat, bcat,
                                           Wcont, bcont, pcat, pcont);
}